// Round 4
// baseline (222.702 us; speedup 1.0000x reference)
//
#include <hip/hip_runtime.h>
#include <math.h>

#define TPB 256
#define EPT 2   // batch elements per thread: b and b+TPB (coalesced pair)

typedef float v2f __attribute__((ext_vector_type(2)));

#define VFMA(a, b, c) __builtin_elementwise_fma((a), (b), (c))
#define VMAX(a, b) __builtin_elementwise_max((a), (b))
#define VMIN(a, b) __builtin_elementwise_min((a), (b))
#define LOG2E 1.4426950408889634f

struct f3 { float a, b, c; };

struct Ptrs {
    const float *temp, *pressure;
    const float *c0, *c1, *c2, *c3, *c4, *c5, *c6;
    const float *lwp, *iwp, *mu, *mub;
    const float *gW1, *gb1, *gW2, *gb2;
    const float *lww, *iww;
    const float *eW1, *eb1, *eW2, *eb2;
    float* out;
    int Bn;
};

static __device__ __forceinline__ v2f sp(float s) { return (v2f){s, s}; }

static __device__ __forceinline__ float fexp2(float x) {
#if __has_builtin(__builtin_amdgcn_exp2f)
    return __builtin_amdgcn_exp2f(x);
#else
    return __expf(x * 0.6931471805599453f);
#endif
}

static __device__ __forceinline__ float fast_rcp(float x) {
    return __builtin_amdgcn_rcpf(x);
}

// ELU, branch-free: elu(h) = max(h,0) + exp2(log2e*min(h,0)) - 1
// (h>=0: min=0 -> exp2(0)=1 -> max+0 = h exactly; h<0: max=0 -> exp(h)-1)
static __device__ __forceinline__ v2f elu2(v2f h) {
    v2f t = VMIN(h, sp(0.f)) * LOG2E;        // pk_min + pk_mul
    v2f e = {fexp2(t.x), fexp2(t.y)};        // 2x trans
    return VMAX(h, sp(0.f)) + e - 1.0f;      // pk_max + 2x pk_add
}

// Per-row gas-net table: NETS[r][s] = net id of species s contributing to row r,
// 255 = absent. Species s: 0=h2o 1=h2o_sq 2=o3 3=co2 4=n2o 5=ch4 6=u.
static __device__ const unsigned char NETS[29][8] = {
    {  0, 23,  52,  65,  74,  77,  86, 255},
    {  1, 24,  53,  66,  75,  78,  87, 255},
    {  2, 25,  54,  67,  76,  79,  88, 255},
    {  3, 26, 255, 255, 255,  80, 255, 255},
    {  4, 27, 255, 255, 255,  81, 255, 255},
    {  5, 28, 255,  68, 255, 255, 255, 255},
    {  6, 29, 255,  69, 255, 255, 255, 255},
    {  3, 30, 255, 255, 255,  82, 255, 255},
    {  4, 31, 255, 255, 255,  83, 255, 255},
    {  9, 32, 255,  70, 255, 255, 255, 255},
    { 10, 33, 255,  71, 255, 255, 255, 255},
    { 11, 34, 255, 255, 255,  84, 255, 255},
    { 12, 35, 255, 255, 255,  85, 255, 255},
    { 13, 36, 255,  72, 255, 255, 255, 255},
    { 14, 37, 255,  73, 255, 255, 255, 255},
    { 15, 38, 255, 255, 255, 255,  89, 255},
    { 16, 39, 255, 255, 255, 255,  90, 255},
    { 17, 40,  55, 255, 255, 255,  91, 255},
    { 18, 41,  56, 255, 255, 255,  92, 255},
    { 19, 42,  57, 255, 255, 255,  93, 255},
    { 20, 43,  58, 255, 255, 255,  94, 255},
    { 21, 44,  59, 255, 255, 255,  95, 255},
    { 22, 45,  60, 255, 255, 255,  96, 255},
    {255, 46, 255, 255, 255, 255, 255, 255},
    {255, 47, 255, 255, 255, 255, 255, 255},
    {255, 48,  61, 255, 255, 255, 255, 255},
    {255, 49,  62, 255, 255, 255, 255, 255},
    {255, 50,  63, 255, 255, 255,  97, 255},
    {255, 51,  64, 255, 255, 255,  98, 255}};

// packed softmax over 3 logits for the A/B pair
static __device__ __forceinline__ void softmax3_v2(v2f o0, v2f o1, v2f o2,
                                                   v2f& r0, v2f& r1, v2f& r2) {
    o0 = VMAX(o0, sp(0.f));                  // ReLU
    o1 = VMAX(o1, sp(0.f));
    o2 = VMAX(o2, sp(0.f));
    v2f mx = VMAX(o0, VMAX(o1, o2));
    v2f nm = mx * (-LOG2E);                  // pk_mul
    v2f a0 = VFMA(o0, sp(LOG2E), nm);        // (o-mx)*log2e as pk_fma
    v2f a1 = VFMA(o1, sp(LOG2E), nm);
    v2f a2 = VFMA(o2, sp(LOG2E), nm);
    v2f e0 = {fexp2(a0.x), fexp2(a0.y)};
    v2f e1 = {fexp2(a1.x), fexp2(a1.y)};
    v2f e2 = {fexp2(a2.x), fexp2(a2.y)};
    v2f ssum = e0 + e1 + e2;                 // 2x pk_add
    v2f rs = {fast_rcp(ssum.x), fast_rcp(ssum.y)};
    r0 = e0 * rs; r1 = e1 * rs; r2 = e2 * rs;
}

// One (row r, batch pair bA/bA+TPB) work item.
template <bool GUARD>
static __device__ __forceinline__ void item_body(const Ptrs& P, int r, int bA,
                                                 bool vB, int bBl) {
    const int Bn = P.Bn;

    const v2f t2  = {P.temp[bA],     P.temp[bBl]};
    const v2f p2  = {P.pressure[bA], P.pressure[bBl]};
    const v2f lwp2 = {P.lwp[bA], P.lwp[bBl]};
    const v2f iwp2 = {P.iwp[bA], P.iwp[bBl]};
    const v2f mu2  = {P.mu[bA],  P.mu[bBl]};
    const v2f mb2  = {P.mub[bA], P.mub[bBl]};

    // ---- gas nets (packed A/B), fully-unrolled species loop ----
    v2f tg = sp(0.f);
    #pragma unroll
    for (int s = 0; s < 7; ++s) {
        const int n = NETS[r][s];                 // wave-uniform -> scalar branch
        if (n != 255) {
            const float* cp =
                (s == 0) ? P.c0 : (s == 1) ? P.c1 :
                (s == 2) ? P.c2 : (s == 3) ? P.c3 :
                (s == 4) ? P.c4 : (s == 5) ? P.c5 : P.c6;
            const v2f cs = {cp[bA], cp[bBl]};          // issue early
            const float4* W1 = (const float4*)(P.gW1 + (n << 4));
            const float4 wt0 = W1[0], wt1 = W1[1];     // temp weights j=0..7
            const float4 wp0 = W1[2], wp1 = W1[3];     // pressure weights
            const float4* B1 = (const float4*)(P.gb1 + (n << 3));
            const float4 bb0 = B1[0], bb1 = B1[1];
            const float4* W2 = (const float4*)(P.gW2 + (n << 3));
            const float4 wo0 = W2[0], wo1 = W2[1];
            v2f acc = sp(P.gb2[n]);
#define GAS_H(WT, WP, BB, WO, K)                                            \
            { v2f h = VFMA(t2, sp((WT).K), VFMA(p2, sp((WP).K), sp((BB).K))); \
              h = elu2(h);                                                   \
              acc = VFMA(h, sp((WO).K), acc); }
            GAS_H(wt0, wp0, bb0, wo0, x)
            GAS_H(wt0, wp0, bb0, wo0, y)
            GAS_H(wt0, wp0, bb0, wo0, z)
            GAS_H(wt0, wp0, bb0, wo0, w)
            GAS_H(wt1, wp1, bb1, wo1, x)
            GAS_H(wt1, wp1, bb1, wo1, y)
            GAS_H(wt1, wp1, bb1, wo1, z)
            GAS_H(wt1, wp1, bb1, wo1, w)
#undef GAS_H
            acc = VMAX(acc, sp(0.f));              // ReLU -> ke
            tg = VFMA(acc, cs, tg);
        }
    }

    // ---- tau composition (packed) ----
    const float lwr = P.lww[r], iwr = P.iww[r];    // uniform
    v2f tlw = lwp2 * lwr;
    v2f tiw = iwp2 * iwr;
    v2f tt = tg + tlw + tiw;
    v2f rtt = {fast_rcp(tt.x), fast_rcp(tt.y)};
    v2f in1 = tlw * rtt;
    v2f in2 = tiw * rtt;
    v2f rmu = {fast_rcp(mu2.x), fast_rcp(mu2.y)};
    v2f rmb = {fast_rcp(mb2.x), fast_rcp(mb2.y)};
    v2f i3d = tt * rmu;
    v2f i3f = tt * rmb;

    float* out = P.out;
    const int idxA = r * Bn + bA;                  // fits int32
    {
        v2f ad = i3d * (-LOG2E);
        v2f af = i3f * (-LOG2E);
        out[idxA] = fexp2(ad.x);                   // t_direct, elem A
        out[29 * Bn + idxA] = fexp2(af.x);         // t_diffuse, elem A
        if (!GUARD || vB) {
            out[idxA + TPB] = fexp2(ad.y);
            out[29 * Bn + idxA + TPB] = fexp2(af.y);
        }
    }

    // ---- extinction net (row r): packed A/B, direct+diffuse share base ----
    const float* w1  = P.eW1 + (r << 6);
    const float* ebv = P.eb1 + (r << 4);
    const float* w2  = P.eW2 + r * 48;
    const float bo0 = P.eb2[r * 3 + 0];
    const float bo1 = P.eb2[r * 3 + 1];
    const float bo2 = P.eb2[r * 3 + 2];

    v2f d0 = sp(bo0), d1 = sp(bo1), d2 = sp(bo2);  // direct logits
    v2f f0 = sp(bo0), f1 = sp(bo1), f2 = sp(bo2);  // diffuse logits

    #pragma unroll
    for (int q = 0; q < 4; ++q) {
        const float4 wA4 = *(const float4*)(w1 + 4 * q);        // in1 weights
        const float4 wB4 = *(const float4*)(w1 + 16 + 4 * q);   // in2 weights
        const float4 wC4 = *(const float4*)(w1 + 32 + 4 * q);   // in3 weights
        const float4 wD4 = *(const float4*)(w1 + 48 + 4 * q);   // mu  weights
        const float4 bj4 = *(const float4*)(ebv + 4 * q);
        const float4 u0  = *(const float4*)(w2 + 12 * q);       // W2 rows
        const float4 u1  = *(const float4*)(w2 + 12 * q + 4);
        const float4 u2  = *(const float4*)(w2 + 12 * q + 8);
#define EXT_H(K, W20, W21, W22)                                               \
        { v2f bs = VFMA(in1, sp((wA4).K), VFMA(in2, sp((wB4).K), sp((bj4).K))); \
          v2f hd = elu2(VFMA(i3d, sp((wC4).K), VFMA(mu2, sp((wD4).K), bs)));   \
          v2f hf = elu2(VFMA(i3f, sp((wC4).K), VFMA(mb2, sp((wD4).K), bs)));   \
          d0 = VFMA(hd, sp(W20), d0); d1 = VFMA(hd, sp(W21), d1);              \
          d2 = VFMA(hd, sp(W22), d2);                                          \
          f0 = VFMA(hf, sp(W20), f0); f1 = VFMA(hf, sp(W21), f1);              \
          f2 = VFMA(hf, sp(W22), f2); }
        EXT_H(x, u0.x, u0.y, u0.z)
        EXT_H(y, u0.w, u1.x, u1.y)
        EXT_H(z, u1.z, u1.w, u2.x)
        EXT_H(w, u2.y, u2.z, u2.w)
#undef EXT_H
    }

    // ---- softmax + packed float3 stores ----
    v2f r0, r1, r2;
    softmax3_v2(d0, d1, d2, r0, r1, r2);
    f3* pdA = (f3*)(out + 58 * Bn) + idxA;          // e_direct (29,B,3)
    pdA[0] = (f3){r0.x, r1.x, r2.x};
    if (!GUARD || vB) pdA[TPB] = (f3){r0.y, r1.y, r2.y};
    softmax3_v2(f0, f1, f2, r0, r1, r2);
    f3* pfA = (f3*)(out + 145 * Bn) + idxA;         // e_diffuse (29,B,3)
    pfA[0] = (f3){r0.x, r1.x, r2.x};
    if (!GUARD || vB) pfA[TPB] = (f3){r0.y, r1.y, r2.y};
}

// Persistent, perfectly-balanced kernel: all blocks co-resident, each
// grid-strides over (row, chunk) items in row-major order (r = it >> yshift)
// so consecutive strides land on different rows (work mixing, no tail).
__global__ __launch_bounds__(TPB) void atm_persist(Ptrs P, int yshift,
                                                   int items, int stride) {
    const int ymask = (1 << yshift) - 1;
    for (int it = blockIdx.x; it < items; it += stride) {
        const int r = it >> yshift;
        const int bA = ((it & ymask) * (TPB * EPT)) + threadIdx.x;
        item_body<false>(P, r, bA, true, bA + TPB);
    }
}

// Fallback: 2D grid, guarded tail.
template <bool GUARD>
__global__ __launch_bounds__(TPB) void atm_legacy(Ptrs P) {
    const int r = blockIdx.x;
    const int bA = blockIdx.y * (TPB * EPT) + threadIdx.x;
    if (GUARD && bA >= P.Bn) return;
    const int bB = bA + TPB;
    bool vB = true;
    int bBl = bB;
    if (GUARD) { vB = (bB < P.Bn); bBl = vB ? bB : bA; }
    item_body<GUARD>(P, r, bA, vB, bBl);
}

extern "C" void kernel_launch(void* const* d_in, const int* in_sizes, int n_in,
                              void* d_out, int out_size, void* d_ws, size_t ws_size,
                              hipStream_t stream) {
    const int Bn = in_sizes[0];  // temp has B elements
    Ptrs P;
    P.temp = (const float*)d_in[0];  P.pressure = (const float*)d_in[1];
    P.c0 = (const float*)d_in[2];    P.c1 = (const float*)d_in[3];
    P.c2 = (const float*)d_in[4];    P.c3 = (const float*)d_in[5];
    P.c4 = (const float*)d_in[6];    P.c5 = (const float*)d_in[7];
    P.c6 = (const float*)d_in[8];
    P.lwp = (const float*)d_in[9];   P.iwp = (const float*)d_in[10];
    P.mu = (const float*)d_in[11];   P.mub = (const float*)d_in[12];
    P.gW1 = (const float*)d_in[13];  P.gb1 = (const float*)d_in[14];
    P.gW2 = (const float*)d_in[15];  P.gb2 = (const float*)d_in[16];
    P.lww = (const float*)d_in[17];  P.iww = (const float*)d_in[18];
    P.eW1 = (const float*)d_in[19];  P.eb1 = (const float*)d_in[20];
    P.eW2 = (const float*)d_in[21];  P.eb2 = (const float*)d_in[22];
    P.out = (float*)d_out;
    P.Bn = Bn;

    const int span = TPB * EPT;                       // 512
    if (Bn % span == 0) {
        const int yc = Bn / span;                     // batch chunks
        if ((yc & (yc - 1)) == 0) {                   // power of two
            int yshift = 0;
            while ((1 << yshift) != yc) ++yshift;
            const int items = 29 * yc;                // 7424 @ B=131072
            const int iters = (items + 2047) / 2048;  // 4
            const int grid  = (items + iters - 1) / iters;  // 1856
            atm_persist<<<grid, TPB, 0, stream>>>(P, yshift, items, grid);
            return;
        }
        dim3 g(29, yc);
        atm_legacy<false><<<g, TPB, 0, stream>>>(P);
        return;
    }
    dim3 g(29, (Bn + span - 1) / span);
    atm_legacy<true><<<g, TPB, 0, stream>>>(P);
}

// Round 5
// 215.757 us; speedup vs baseline: 1.0322x; 1.0322x over previous
//
#include <hip/hip_runtime.h>
#include <math.h>

#define TPB 256

typedef float v2f __attribute__((ext_vector_type(2)));

#define VFMA(a, b, c) __builtin_elementwise_fma((a), (b), (c))
#define VMAX(a, b) __builtin_elementwise_max((a), (b))
#define VMIN(a, b) __builtin_elementwise_min((a), (b))
#define LOG2E 1.4426950408889634f

struct f3 { float a, b, c; };

struct Ptrs {
    const float *temp, *pressure;
    const float *c0, *c1, *c2, *c3, *c4, *c5, *c6;
    const float *lwp, *iwp, *mu, *mub;
    const float *gW1, *gb1, *gW2, *gb2;
    const float *lww, *iww;
    const float *eW1, *eb1, *eW2, *eb2;
    float* out;
    int Bn;
};

static __device__ __forceinline__ v2f sp(float s) { return (v2f){s, s}; }

static __device__ __forceinline__ float fexp2(float x) {
#if __has_builtin(__builtin_amdgcn_exp2f)
    return __builtin_amdgcn_exp2f(x);
#else
    return __expf(x * 0.6931471805599453f);
#endif
}

static __device__ __forceinline__ float fast_rcp(float x) {
    return __builtin_amdgcn_rcpf(x);
}

// ELU, branch-free: elu(h) = max(h,0) + exp2(log2e*min(h,0)) - 1
static __device__ __forceinline__ v2f elu2(v2f h) {
    v2f t = VMIN(h, sp(0.f)) * LOG2E;        // pk_min + pk_mul
    v2f e = {fexp2(t.x), fexp2(t.y)};        // 2x trans
    return VMAX(h, sp(0.f)) + e - 1.0f;      // pk_max + 2x pk_add
}

// Per-row gas-net table: NETS[r][s] = net id of species s contributing to row r,
// 255 = absent. Species s: 0=h2o 1=h2o_sq 2=o3 3=co2 4=n2o 5=ch4 6=u.
static __device__ const unsigned char NETS[29][8] = {
    {  0, 23,  52,  65,  74,  77,  86, 255},
    {  1, 24,  53,  66,  75,  78,  87, 255},
    {  2, 25,  54,  67,  76,  79,  88, 255},
    {  3, 26, 255, 255, 255,  80, 255, 255},
    {  4, 27, 255, 255, 255,  81, 255, 255},
    {  5, 28, 255,  68, 255, 255, 255, 255},
    {  6, 29, 255,  69, 255, 255, 255, 255},
    {  3, 30, 255, 255, 255,  82, 255, 255},
    {  4, 31, 255, 255, 255,  83, 255, 255},
    {  9, 32, 255,  70, 255, 255, 255, 255},
    { 10, 33, 255,  71, 255, 255, 255, 255},
    { 11, 34, 255, 255, 255,  84, 255, 255},
    { 12, 35, 255, 255, 255,  85, 255, 255},
    { 13, 36, 255,  72, 255, 255, 255, 255},
    { 14, 37, 255,  73, 255, 255, 255, 255},
    { 15, 38, 255, 255, 255, 255,  89, 255},
    { 16, 39, 255, 255, 255, 255,  90, 255},
    { 17, 40,  55, 255, 255, 255,  91, 255},
    { 18, 41,  56, 255, 255, 255,  92, 255},
    { 19, 42,  57, 255, 255, 255,  93, 255},
    { 20, 43,  58, 255, 255, 255,  94, 255},
    { 21, 44,  59, 255, 255, 255,  95, 255},
    { 22, 45,  60, 255, 255, 255,  96, 255},
    {255, 46, 255, 255, 255, 255, 255, 255},
    {255, 47, 255, 255, 255, 255, 255, 255},
    {255, 48,  61, 255, 255, 255, 255, 255},
    {255, 49,  62, 255, 255, 255, 255, 255},
    {255, 50,  63, 255, 255, 255,  97, 255},
    {255, 51,  64, 255, 255, 255,  98, 255}};

// packed softmax over 3 logits for an A/B pair
static __device__ __forceinline__ void softmax3_v2(v2f o0, v2f o1, v2f o2,
                                                   v2f& r0, v2f& r1, v2f& r2) {
    o0 = VMAX(o0, sp(0.f));                  // ReLU
    o1 = VMAX(o1, sp(0.f));
    o2 = VMAX(o2, sp(0.f));
    v2f mx = VMAX(o0, VMAX(o1, o2));
    v2f nm = mx * (-LOG2E);
    v2f x0 = VFMA(o0, sp(LOG2E), nm);
    v2f x1 = VFMA(o1, sp(LOG2E), nm);
    v2f x2 = VFMA(o2, sp(LOG2E), nm);
    v2f e0 = {fexp2(x0.x), fexp2(x0.y)};
    v2f e1 = {fexp2(x1.x), fexp2(x1.y)};
    v2f e2 = {fexp2(x2.x), fexp2(x2.y)};
    v2f ssum = e0 + e1 + e2;
    v2f rs = {fast_rcp(ssum.x), fast_rcp(ssum.y)};
    r0 = e0 * rs; r1 = e1 * rs; r2 = e2 * rs;
}

// EPT=4: each thread handles elements a0, a0+TPB, a0+2*TPB, a0+3*TPB as two
// packed pairs (pair0 = {a0,a1}, pair1 = {a2,a3}). Static 2D grid: weight
// s_loads depend only on blockIdx.x -> hoisted/pipelined by the compiler.
template <bool GUARD>
__global__ __launch_bounds__(TPB) void atm4(Ptrs P) {
    const int r = blockIdx.x;                      // uniform row 0..28
    const int Bn = P.Bn;
    const int a0 = blockIdx.y * (TPB * 4) + threadIdx.x;
    if (GUARD && a0 >= Bn) return;
    int a1 = a0 + TPB, a2 = a0 + 2 * TPB, a3 = a0 + 3 * TPB;
    bool v1 = true, v2 = true, v3 = true;
    if (GUARD) {
        v1 = a1 < Bn; v2 = a2 < Bn; v3 = a3 < Bn;
        if (!v1) a1 = a0;
        if (!v2) a2 = a0;
        if (!v3) a3 = a0;
    }

    // ---- packed inputs: two independent pairs ----
    const v2f T0  = {P.temp[a0], P.temp[a1]},         T1  = {P.temp[a2], P.temp[a3]};
    const v2f Pr0 = {P.pressure[a0], P.pressure[a1]}, Pr1 = {P.pressure[a2], P.pressure[a3]};
    const v2f LW0 = {P.lwp[a0], P.lwp[a1]},           LW1 = {P.lwp[a2], P.lwp[a3]};
    const v2f IW0 = {P.iwp[a0], P.iwp[a1]},           IW1 = {P.iwp[a2], P.iwp[a3]};
    const v2f MU0 = {P.mu[a0], P.mu[a1]},             MU1 = {P.mu[a2], P.mu[a3]};
    const v2f MB0 = {P.mub[a0], P.mub[a1]},           MB1 = {P.mub[a2], P.mub[a3]};

    // ---- gas nets, fully-unrolled species loop, 4 elements per weight fetch ----
    v2f tg0 = sp(0.f), tg1 = sp(0.f);
    #pragma unroll
    for (int s = 0; s < 7; ++s) {
        const int n = NETS[r][s];                  // wave-uniform -> scalar branch
        if (n != 255) {
            const float* cp =
                (s == 0) ? P.c0 : (s == 1) ? P.c1 :
                (s == 2) ? P.c2 : (s == 3) ? P.c3 :
                (s == 4) ? P.c4 : (s == 5) ? P.c5 : P.c6;
            const v2f cs0 = {cp[a0], cp[a1]};
            const v2f cs1 = {cp[a2], cp[a3]};
            const float4* W1 = (const float4*)(P.gW1 + (n << 4));
            const float4 wt0 = W1[0], wt1 = W1[1];     // temp weights j=0..7
            const float4 wp0 = W1[2], wp1 = W1[3];     // pressure weights
            const float4* B1 = (const float4*)(P.gb1 + (n << 3));
            const float4 bb0 = B1[0], bb1 = B1[1];
            const float4* W2 = (const float4*)(P.gW2 + (n << 3));
            const float4 wo0 = W2[0], wo1 = W2[1];
            v2f acc0 = sp(P.gb2[n]), acc1 = acc0;
#define GAS_H(WT, WP, BB, WO, K)                                              \
            { v2f h0 = VFMA(T0, sp((WT).K), VFMA(Pr0, sp((WP).K), sp((BB).K))); \
              v2f h1 = VFMA(T1, sp((WT).K), VFMA(Pr1, sp((WP).K), sp((BB).K))); \
              h0 = elu2(h0); h1 = elu2(h1);                                    \
              acc0 = VFMA(h0, sp((WO).K), acc0);                               \
              acc1 = VFMA(h1, sp((WO).K), acc1); }
            GAS_H(wt0, wp0, bb0, wo0, x)
            GAS_H(wt0, wp0, bb0, wo0, y)
            GAS_H(wt0, wp0, bb0, wo0, z)
            GAS_H(wt0, wp0, bb0, wo0, w)
            GAS_H(wt1, wp1, bb1, wo1, x)
            GAS_H(wt1, wp1, bb1, wo1, y)
            GAS_H(wt1, wp1, bb1, wo1, z)
            GAS_H(wt1, wp1, bb1, wo1, w)
#undef GAS_H
            acc0 = VMAX(acc0, sp(0.f));            // ReLU -> ke
            acc1 = VMAX(acc1, sp(0.f));
            tg0 = VFMA(acc0, cs0, tg0);
            tg1 = VFMA(acc1, cs1, tg1);
        }
    }

    // ---- tau composition (both pairs) ----
    const float lwr = P.lww[r], iwr = P.iww[r];    // uniform
    v2f tlw0 = LW0 * lwr, tlw1 = LW1 * lwr;
    v2f tiw0 = IW0 * iwr, tiw1 = IW1 * iwr;
    v2f tt0 = tg0 + tlw0 + tiw0;
    v2f tt1 = tg1 + tlw1 + tiw1;
    v2f rtt0 = {fast_rcp(tt0.x), fast_rcp(tt0.y)};
    v2f rtt1 = {fast_rcp(tt1.x), fast_rcp(tt1.y)};
    v2f in10 = tlw0 * rtt0, in20 = tiw0 * rtt0;
    v2f in11 = tlw1 * rtt1, in21 = tiw1 * rtt1;
    v2f rmu0 = {fast_rcp(MU0.x), fast_rcp(MU0.y)};
    v2f rmu1 = {fast_rcp(MU1.x), fast_rcp(MU1.y)};
    v2f rmb0 = {fast_rcp(MB0.x), fast_rcp(MB0.y)};
    v2f rmb1 = {fast_rcp(MB1.x), fast_rcp(MB1.y)};
    v2f i3d0 = tt0 * rmu0, i3d1 = tt1 * rmu1;
    v2f i3f0 = tt0 * rmb0, i3f1 = tt1 * rmb1;

    float* out = P.out;
    const int idx0 = r * Bn + a0;                  // fits int32
    {
        v2f ad0 = i3d0 * (-LOG2E), ad1 = i3d1 * (-LOG2E);
        v2f af0 = i3f0 * (-LOG2E), af1 = i3f1 * (-LOG2E);
        out[idx0] = fexp2(ad0.x);
        out[29 * Bn + idx0] = fexp2(af0.x);
        if (!GUARD || v1) {
            out[idx0 + TPB] = fexp2(ad0.y);
            out[29 * Bn + idx0 + TPB] = fexp2(af0.y);
        }
        if (!GUARD || v2) {
            out[idx0 + 2 * TPB] = fexp2(ad1.x);
            out[29 * Bn + idx0 + 2 * TPB] = fexp2(af1.x);
        }
        if (!GUARD || v3) {
            out[idx0 + 3 * TPB] = fexp2(ad1.y);
            out[29 * Bn + idx0 + 3 * TPB] = fexp2(af1.y);
        }
    }

    // ---- extinction net (row r): 2 pairs x 2 passes, shared weights,
    //      shared (in1,in2,b1) partial across passes ----
    const float* w1  = P.eW1 + (r << 6);
    const float* ebv = P.eb1 + (r << 4);
    const float* w2  = P.eW2 + r * 48;
    const float bo0 = P.eb2[r * 3 + 0];
    const float bo1 = P.eb2[r * 3 + 1];
    const float bo2 = P.eb2[r * 3 + 2];

    v2f d00 = sp(bo0), d01 = sp(bo1), d02 = sp(bo2);  // pair0 direct
    v2f f00 = sp(bo0), f01 = sp(bo1), f02 = sp(bo2);  // pair0 diffuse
    v2f d10 = sp(bo0), d11 = sp(bo1), d12 = sp(bo2);  // pair1 direct
    v2f f10 = sp(bo0), f11 = sp(bo1), f12 = sp(bo2);  // pair1 diffuse

    #pragma unroll
    for (int q = 0; q < 4; ++q) {
        const float4 wA4 = *(const float4*)(w1 + 4 * q);        // in1 weights
        const float4 wB4 = *(const float4*)(w1 + 16 + 4 * q);   // in2 weights
        const float4 wC4 = *(const float4*)(w1 + 32 + 4 * q);   // in3 weights
        const float4 wD4 = *(const float4*)(w1 + 48 + 4 * q);   // mu  weights
        const float4 bj4 = *(const float4*)(ebv + 4 * q);
        const float4 u0  = *(const float4*)(w2 + 12 * q);       // W2 rows
        const float4 u1  = *(const float4*)(w2 + 12 * q + 4);
        const float4 u2  = *(const float4*)(w2 + 12 * q + 8);
#define EXT_H(K, W20, W21, W22)                                                 \
        { v2f bs0 = VFMA(in10, sp((wA4).K), VFMA(in20, sp((wB4).K), sp((bj4).K))); \
          v2f bs1 = VFMA(in11, sp((wA4).K), VFMA(in21, sp((wB4).K), sp((bj4).K))); \
          v2f hd0 = elu2(VFMA(i3d0, sp((wC4).K), VFMA(MU0, sp((wD4).K), bs0)));  \
          v2f hf0 = elu2(VFMA(i3f0, sp((wC4).K), VFMA(MB0, sp((wD4).K), bs0)));  \
          v2f hd1 = elu2(VFMA(i3d1, sp((wC4).K), VFMA(MU1, sp((wD4).K), bs1)));  \
          v2f hf1 = elu2(VFMA(i3f1, sp((wC4).K), VFMA(MB1, sp((wD4).K), bs1)));  \
          d00 = VFMA(hd0, sp(W20), d00); d01 = VFMA(hd0, sp(W21), d01);          \
          d02 = VFMA(hd0, sp(W22), d02);                                         \
          f00 = VFMA(hf0, sp(W20), f00); f01 = VFMA(hf0, sp(W21), f01);          \
          f02 = VFMA(hf0, sp(W22), f02);                                         \
          d10 = VFMA(hd1, sp(W20), d10); d11 = VFMA(hd1, sp(W21), d11);          \
          d12 = VFMA(hd1, sp(W22), d12);                                         \
          f10 = VFMA(hf1, sp(W20), f10); f11 = VFMA(hf1, sp(W21), f11);          \
          f12 = VFMA(hf1, sp(W22), f12); }
        EXT_H(x, u0.x, u0.y, u0.z)
        EXT_H(y, u0.w, u1.x, u1.y)
        EXT_H(z, u1.z, u1.w, u2.x)
        EXT_H(w, u2.y, u2.z, u2.w)
#undef EXT_H
    }

    // ---- softmax + packed float3 stores ----
    v2f r0, r1, r2;
    f3* pd = (f3*)(out + 58 * Bn) + idx0;           // e_direct  (29,B,3)
    f3* pf = (f3*)(out + 145 * Bn) + idx0;          // e_diffuse (29,B,3)

    softmax3_v2(d00, d01, d02, r0, r1, r2);
    pd[0] = (f3){r0.x, r1.x, r2.x};
    if (!GUARD || v1) pd[TPB] = (f3){r0.y, r1.y, r2.y};
    softmax3_v2(d10, d11, d12, r0, r1, r2);
    if (!GUARD || v2) pd[2 * TPB] = (f3){r0.x, r1.x, r2.x};
    if (!GUARD || v3) pd[3 * TPB] = (f3){r0.y, r1.y, r2.y};

    softmax3_v2(f00, f01, f02, r0, r1, r2);
    pf[0] = (f3){r0.x, r1.x, r2.x};
    if (!GUARD || v1) pf[TPB] = (f3){r0.y, r1.y, r2.y};
    softmax3_v2(f10, f11, f12, r0, r1, r2);
    if (!GUARD || v2) pf[2 * TPB] = (f3){r0.x, r1.x, r2.x};
    if (!GUARD || v3) pf[3 * TPB] = (f3){r0.y, r1.y, r2.y};
}

extern "C" void kernel_launch(void* const* d_in, const int* in_sizes, int n_in,
                              void* d_out, int out_size, void* d_ws, size_t ws_size,
                              hipStream_t stream) {
    const int Bn = in_sizes[0];  // temp has B elements
    Ptrs P;
    P.temp = (const float*)d_in[0];  P.pressure = (const float*)d_in[1];
    P.c0 = (const float*)d_in[2];    P.c1 = (const float*)d_in[3];
    P.c2 = (const float*)d_in[4];    P.c3 = (const float*)d_in[5];
    P.c4 = (const float*)d_in[6];    P.c5 = (const float*)d_in[7];
    P.c6 = (const float*)d_in[8];
    P.lwp = (const float*)d_in[9];   P.iwp = (const float*)d_in[10];
    P.mu = (const float*)d_in[11];   P.mub = (const float*)d_in[12];
    P.gW1 = (const float*)d_in[13];  P.gb1 = (const float*)d_in[14];
    P.gW2 = (const float*)d_in[15];  P.gb2 = (const float*)d_in[16];
    P.lww = (const float*)d_in[17];  P.iww = (const float*)d_in[18];
    P.eW1 = (const float*)d_in[19];  P.eb1 = (const float*)d_in[20];
    P.eW2 = (const float*)d_in[21];  P.eb2 = (const float*)d_in[22];
    P.out = (float*)d_out;
    P.Bn = Bn;

    const int span = TPB * 4;                       // 1024 elements per block
    dim3 g(29, (Bn + span - 1) / span);
    if (Bn % span == 0) {
        atm4<false><<<g, TPB, 0, stream>>>(P);
    } else {
        atm4<true><<<g, TPB, 0, stream>>>(P);
    }
}

// Round 6
// 214.982 us; speedup vs baseline: 1.0359x; 1.0036x over previous
//
#include <hip/hip_runtime.h>
#include <math.h>

#define TPB 256

typedef float v2f __attribute__((ext_vector_type(2)));

#define VFMA(a, b, c) __builtin_elementwise_fma((a), (b), (c))
#define VMAX(a, b) __builtin_elementwise_max((a), (b))
#define VMIN(a, b) __builtin_elementwise_min((a), (b))
#define LOG2E 1.4426950408889634f

struct f3 { float a, b, c; };

struct Ptrs {
    const float *temp, *pressure;
    const float *c0, *c1, *c2, *c3, *c4, *c5, *c6;
    const float *lwp, *iwp, *mu, *mub;
    const float *gW1, *gb1, *gW2, *gb2;
    const float *lww, *iww;
    const float *eW1, *eb1, *eW2, *eb2;
    float* out;
    int Bn;
};

static __device__ __forceinline__ v2f sp(float s) { return (v2f){s, s}; }

static __device__ __forceinline__ float fexp2(float x) {
#if __has_builtin(__builtin_amdgcn_exp2f)
    return __builtin_amdgcn_exp2f(x);
#else
    return __expf(x * 0.6931471805599453f);
#endif
}

static __device__ __forceinline__ float fast_rcp(float x) {
    return __builtin_amdgcn_rcpf(x);
}

// ELU, branch-free: elu(h) = max(h,0) + exp2(log2e*min(h,0)) - 1
static __device__ __forceinline__ v2f elu2(v2f h) {
    v2f t = VMIN(h, sp(0.f)) * LOG2E;        // pk_min + pk_mul
    v2f e = {fexp2(t.x), fexp2(t.y)};        // 2x trans
    return VMAX(h, sp(0.f)) + e - 1.0f;      // pk_max + 2x pk_add
}

// Per-row gas-net table: NETS[r][s] = net id of species s contributing to row r,
// 255 = absent. Species s: 0=h2o 1=h2o_sq 2=o3 3=co2 4=n2o 5=ch4 6=u.
static __device__ const unsigned char NETS[29][8] = {
    {  0, 23,  52,  65,  74,  77,  86, 255},
    {  1, 24,  53,  66,  75,  78,  87, 255},
    {  2, 25,  54,  67,  76,  79,  88, 255},
    {  3, 26, 255, 255, 255,  80, 255, 255},
    {  4, 27, 255, 255, 255,  81, 255, 255},
    {  5, 28, 255,  68, 255, 255, 255, 255},
    {  6, 29, 255,  69, 255, 255, 255, 255},
    {  3, 30, 255, 255, 255,  82, 255, 255},
    {  4, 31, 255, 255, 255,  83, 255, 255},
    {  9, 32, 255,  70, 255, 255, 255, 255},
    { 10, 33, 255,  71, 255, 255, 255, 255},
    { 11, 34, 255, 255, 255,  84, 255, 255},
    { 12, 35, 255, 255, 255,  85, 255, 255},
    { 13, 36, 255,  72, 255, 255, 255, 255},
    { 14, 37, 255,  73, 255, 255, 255, 255},
    { 15, 38, 255, 255, 255, 255,  89, 255},
    { 16, 39, 255, 255, 255, 255,  90, 255},
    { 17, 40,  55, 255, 255, 255,  91, 255},
    { 18, 41,  56, 255, 255, 255,  92, 255},
    { 19, 42,  57, 255, 255, 255,  93, 255},
    { 20, 43,  58, 255, 255, 255,  94, 255},
    { 21, 44,  59, 255, 255, 255,  95, 255},
    { 22, 45,  60, 255, 255, 255,  96, 255},
    {255, 46, 255, 255, 255, 255, 255, 255},
    {255, 47, 255, 255, 255, 255, 255, 255},
    {255, 48,  61, 255, 255, 255, 255, 255},
    {255, 49,  62, 255, 255, 255, 255, 255},
    {255, 50,  63, 255, 255, 255,  97, 255},
    {255, 51,  64, 255, 255, 255,  98, 255}};

// packed softmax over 3 logits for the adjacent pair
static __device__ __forceinline__ void softmax3_v2(v2f o0, v2f o1, v2f o2,
                                                   v2f& r0, v2f& r1, v2f& r2) {
    o0 = VMAX(o0, sp(0.f));                  // ReLU
    o1 = VMAX(o1, sp(0.f));
    o2 = VMAX(o2, sp(0.f));
    v2f mx = VMAX(o0, VMAX(o1, o2));
    v2f nm = mx * (-LOG2E);
    v2f x0 = VFMA(o0, sp(LOG2E), nm);
    v2f x1 = VFMA(o1, sp(LOG2E), nm);
    v2f x2 = VFMA(o2, sp(LOG2E), nm);
    v2f e0 = {fexp2(x0.x), fexp2(x0.y)};
    v2f e1 = {fexp2(x1.x), fexp2(x1.y)};
    v2f e2 = {fexp2(x2.x), fexp2(x2.y)};
    v2f ssum = e0 + e1 + e2;
    v2f rs = {fast_rcp(ssum.x), fast_rcp(ssum.y)};
    r0 = e0 * rs; r1 = e1 * rs; r2 = e2 * rs;
}

// EPT=2, ADJACENT pair (e0, e0+1): all per-batch inputs load as one dwordx2,
// t-stores as dwordx2, e-stores as two adjacent f3 (24B contiguous per lane).
template <bool GUARD>
__global__ __launch_bounds__(TPB) void atm2(Ptrs P) {
    const int r = blockIdx.x;                      // uniform row 0..28
    const int Bn = P.Bn;
    const int e0 = blockIdx.y * (2 * TPB) + 2 * threadIdx.x;
    if (GUARD && e0 >= Bn) return;
    const bool v1 = !GUARD || (e0 + 1 < Bn);
    const int e1 = v1 ? e0 + 1 : e0;
    const int gid = e0 >> 1;

#define LD2(p) (GUARD ? (v2f){(p)[e0], (p)[e1]} \
                      : *(const v2f*)((const float2*)(p) + gid))
    const v2f t2  = LD2(P.temp);
    const v2f p2  = LD2(P.pressure);
    v2f comp2[7];
    comp2[0] = LD2(P.c0); comp2[1] = LD2(P.c1); comp2[2] = LD2(P.c2);
    comp2[3] = LD2(P.c3); comp2[4] = LD2(P.c4); comp2[5] = LD2(P.c5);
    comp2[6] = LD2(P.c6);
    const v2f lwp2 = LD2(P.lwp);
    const v2f iwp2 = LD2(P.iwp);
    const v2f mu2  = LD2(P.mu);
    const v2f mb2  = LD2(P.mub);
#undef LD2

    // ---- gas nets (packed adjacent pair), fully-unrolled species loop ----
    v2f tg = sp(0.f);
    #pragma unroll
    for (int s = 0; s < 7; ++s) {
        const int n = NETS[r][s];                  // wave-uniform -> scalar branch
        if (n != 255) {
            const float4* W1 = (const float4*)(P.gW1 + (n << 4));
            const float4 wt0 = W1[0], wt1 = W1[1];     // temp weights j=0..7
            const float4 wp0 = W1[2], wp1 = W1[3];     // pressure weights
            const float4* B1 = (const float4*)(P.gb1 + (n << 3));
            const float4 bb0 = B1[0], bb1 = B1[1];
            const float4* W2 = (const float4*)(P.gW2 + (n << 3));
            const float4 wo0 = W2[0], wo1 = W2[1];
            v2f acc = sp(P.gb2[n]);
#define GAS_H(WT, WP, BB, WO, K)                                            \
            { v2f h = VFMA(t2, sp((WT).K), VFMA(p2, sp((WP).K), sp((BB).K))); \
              h = elu2(h);                                                   \
              acc = VFMA(h, sp((WO).K), acc); }
            GAS_H(wt0, wp0, bb0, wo0, x)
            GAS_H(wt0, wp0, bb0, wo0, y)
            GAS_H(wt0, wp0, bb0, wo0, z)
            GAS_H(wt0, wp0, bb0, wo0, w)
            GAS_H(wt1, wp1, bb1, wo1, x)
            GAS_H(wt1, wp1, bb1, wo1, y)
            GAS_H(wt1, wp1, bb1, wo1, z)
            GAS_H(wt1, wp1, bb1, wo1, w)
#undef GAS_H
            acc = VMAX(acc, sp(0.f));              // ReLU -> ke
            tg = VFMA(acc, comp2[s], tg);          // s compile-time
        }
    }

    // ---- tau composition (packed) ----
    const float lwr = P.lww[r], iwr = P.iww[r];    // uniform
    v2f tlw = lwp2 * lwr;
    v2f tiw = iwp2 * iwr;
    v2f tt = tg + tlw + tiw;
    v2f rtt = {fast_rcp(tt.x), fast_rcp(tt.y)};
    v2f in1 = tlw * rtt;
    v2f in2 = tiw * rtt;
    v2f rmu = {fast_rcp(mu2.x), fast_rcp(mu2.y)};
    v2f rmb = {fast_rcp(mb2.x), fast_rcp(mb2.y)};
    v2f i3d = tt * rmu;
    v2f i3f = tt * rmb;

    float* out = P.out;
    const int idx0 = r * Bn + e0;                  // even; fits int32
    {
        v2f ad = i3d * (-LOG2E);
        v2f af = i3f * (-LOG2E);
        v2f td = {fexp2(ad.x), fexp2(ad.y)};
        v2f tf = {fexp2(af.x), fexp2(af.y)};
        if (!GUARD) {
            *(v2f*)(out + idx0) = td;              // dwordx2, 8B-aligned
            *(v2f*)(out + 29 * Bn + idx0) = tf;
        } else {
            out[idx0] = td.x;
            out[29 * Bn + idx0] = tf.x;
            if (v1) {
                out[idx0 + 1] = td.y;
                out[29 * Bn + idx0 + 1] = tf.y;
            }
        }
    }

    // ---- extinction net (row r): packed pair, direct+diffuse share base ----
    const float* w1  = P.eW1 + (r << 6);
    const float* ebv = P.eb1 + (r << 4);
    const float* w2  = P.eW2 + r * 48;
    const float bo0 = P.eb2[r * 3 + 0];
    const float bo1 = P.eb2[r * 3 + 1];
    const float bo2 = P.eb2[r * 3 + 2];

    v2f d0 = sp(bo0), d1 = sp(bo1), d2 = sp(bo2);  // direct logits
    v2f f0 = sp(bo0), f1 = sp(bo1), f2 = sp(bo2);  // diffuse logits

    #pragma unroll
    for (int q = 0; q < 4; ++q) {
        const float4 wA4 = *(const float4*)(w1 + 4 * q);        // in1 weights
        const float4 wB4 = *(const float4*)(w1 + 16 + 4 * q);   // in2 weights
        const float4 wC4 = *(const float4*)(w1 + 32 + 4 * q);   // in3 weights
        const float4 wD4 = *(const float4*)(w1 + 48 + 4 * q);   // mu  weights
        const float4 bj4 = *(const float4*)(ebv + 4 * q);
        const float4 u0  = *(const float4*)(w2 + 12 * q);       // W2 rows
        const float4 u1  = *(const float4*)(w2 + 12 * q + 4);
        const float4 u2  = *(const float4*)(w2 + 12 * q + 8);
#define EXT_H(K, W20, W21, W22)                                               \
        { v2f bs = VFMA(in1, sp((wA4).K), VFMA(in2, sp((wB4).K), sp((bj4).K))); \
          v2f hd = elu2(VFMA(i3d, sp((wC4).K), VFMA(mu2, sp((wD4).K), bs)));   \
          v2f hf = elu2(VFMA(i3f, sp((wC4).K), VFMA(mb2, sp((wD4).K), bs)));   \
          d0 = VFMA(hd, sp(W20), d0); d1 = VFMA(hd, sp(W21), d1);              \
          d2 = VFMA(hd, sp(W22), d2);                                          \
          f0 = VFMA(hf, sp(W20), f0); f1 = VFMA(hf, sp(W21), f1);              \
          f2 = VFMA(hf, sp(W22), f2); }
        EXT_H(x, u0.x, u0.y, u0.z)
        EXT_H(y, u0.w, u1.x, u1.y)
        EXT_H(z, u1.z, u1.w, u2.x)
        EXT_H(w, u2.y, u2.z, u2.w)
#undef EXT_H
    }

    // ---- softmax + adjacent f3 stores ----
    v2f r0, r1, r2;
    softmax3_v2(d0, d1, d2, r0, r1, r2);
    f3* pd = (f3*)(out + 58 * Bn) + idx0;           // e_direct (29,B,3)
    pd[0] = (f3){r0.x, r1.x, r2.x};
    if (v1) pd[1] = (f3){r0.y, r1.y, r2.y};
    softmax3_v2(f0, f1, f2, r0, r1, r2);
    f3* pf = (f3*)(out + 145 * Bn) + idx0;          // e_diffuse (29,B,3)
    pf[0] = (f3){r0.x, r1.x, r2.x};
    if (v1) pf[1] = (f3){r0.y, r1.y, r2.y};
}

extern "C" void kernel_launch(void* const* d_in, const int* in_sizes, int n_in,
                              void* d_out, int out_size, void* d_ws, size_t ws_size,
                              hipStream_t stream) {
    const int Bn = in_sizes[0];  // temp has B elements
    Ptrs P;
    P.temp = (const float*)d_in[0];  P.pressure = (const float*)d_in[1];
    P.c0 = (const float*)d_in[2];    P.c1 = (const float*)d_in[3];
    P.c2 = (const float*)d_in[4];    P.c3 = (const float*)d_in[5];
    P.c4 = (const float*)d_in[6];    P.c5 = (const float*)d_in[7];
    P.c6 = (const float*)d_in[8];
    P.lwp = (const float*)d_in[9];   P.iwp = (const float*)d_in[10];
    P.mu = (const float*)d_in[11];   P.mub = (const float*)d_in[12];
    P.gW1 = (const float*)d_in[13];  P.gb1 = (const float*)d_in[14];
    P.gW2 = (const float*)d_in[15];  P.gb2 = (const float*)d_in[16];
    P.lww = (const float*)d_in[17];  P.iww = (const float*)d_in[18];
    P.eW1 = (const float*)d_in[19];  P.eb1 = (const float*)d_in[20];
    P.eW2 = (const float*)d_in[21];  P.eb2 = (const float*)d_in[22];
    P.out = (float*)d_out;
    P.Bn = Bn;

    const int span = 2 * TPB;                       // 512 elements per block
    dim3 g(29, (Bn + span - 1) / span);
    if (Bn % span == 0) {
        atm2<false><<<g, TPB, 0, stream>>>(P);
    } else {
        atm2<true><<<g, TPB, 0, stream>>>(P);
    }
}